// Round 3
// baseline (1076.421 us; speedup 1.0000x reference)
//
#include <hip/hip_runtime.h>
#include <hip/hip_bf16.h>
#include <stdint.h>

#define B_ 2
#define T_ 2048
#define C_ 1024
#define H_ 16
#define D_ 64

typedef __attribute__((ext_vector_type(8))) short short8;
typedef __attribute__((ext_vector_type(4))) float floatx4;

__device__ __forceinline__ float bf2f(uint16_t b) {
    return __uint_as_float(((uint32_t)b) << 16);
}
__device__ __forceinline__ uint16_t f2b(float f) {
    __hip_bfloat16 h = __float2bfloat16(f);  // RNE
    return *(uint16_t*)&h;
}

// ---- canonicalize x: fp32 -> bf16 -----------------------------------------
__global__ void canon_x(const float* __restrict__ in, uint16_t* __restrict__ out,
                        int n) {
    int i = (blockIdx.x * 256 + threadIdx.x) * 4;
    if (i >= n) return;
    float4 v = *(const float4*)(in + i);
    out[i + 0] = f2b(v.x);
    out[i + 1] = f2b(v.y);
    out[i + 2] = f2b(v.z);
    out[i + 3] = f2b(v.w);
}

// ---- transpose + convert: in [R,W] fp32 -> out [W,R] bf16 -----------------
__global__ void transpose_conv(const float* __restrict__ in, uint16_t* __restrict__ out,
                               int R, int W) {
    __shared__ uint16_t tile[32][33];
    int tx = threadIdx.x, ty = threadIdx.y;
    int c0 = blockIdx.x * 32, r0 = blockIdx.y * 32;
    #pragma unroll
    for (int i = 0; i < 32; i += 8)
        tile[ty + i][tx] = f2b(in[(size_t)(r0 + ty + i) * W + (c0 + tx)]);
    __syncthreads();
    #pragma unroll
    for (int i = 0; i < 32; i += 8)
        out[(size_t)(c0 + ty + i) * R + (r0 + tx)] = tile[tx][ty + i];
}

// ------- GEMM: C[M,N] = A[M,K] @ Bt[N,K]^T ; bf16 in, fp32 acc -------------
// 128x128 tile, 256 threads (4 waves, each 64x64 = 4x4 of 16x16x32 MFMA).
// OUT_F32: write float, else write bf16 bits.
template <bool OUT_F32>
__global__ __launch_bounds__(256)
void gemm_bt(const uint16_t* __restrict__ A, const uint16_t* __restrict__ Bt,
             void* __restrict__ Cv, int M, int N, int K) {
    __shared__ uint16_t As[128][32];
    __shared__ uint16_t Bs[128][32];
    int tid = threadIdx.x;
    int wave = tid >> 6, lane = tid & 63;
    int quad = lane >> 4, l16 = lane & 15;
    int wr = (wave >> 1) * 64, wc = (wave & 1) * 64;
    int row0 = blockIdx.x * 128, col0 = blockIdx.y * 128;
    int srow = tid >> 1, scol = (tid & 1) * 16;

    floatx4 acc[4][4];
    #pragma unroll
    for (int i = 0; i < 4; i++)
        #pragma unroll
        for (int j = 0; j < 4; j++)
            acc[i][j] = (floatx4){0.f, 0.f, 0.f, 0.f};

    for (int k0 = 0; k0 < K; k0 += 32) {
        const uint4* ga = (const uint4*)(A + (size_t)(row0 + srow) * K + k0 + scol);
        const uint4* gb = (const uint4*)(Bt + (size_t)(col0 + srow) * K + k0 + scol);
        uint4 a0 = ga[0], a1 = ga[1];
        uint4 b0 = gb[0], b1 = gb[1];
        __syncthreads();
        *(uint4*)&As[srow][scol]     = a0;
        *(uint4*)&As[srow][scol + 8] = a1;
        *(uint4*)&Bs[srow][scol]     = b0;
        *(uint4*)&Bs[srow][scol + 8] = b1;
        __syncthreads();
        short8 af[4], bf[4];
        #pragma unroll
        for (int i = 0; i < 4; i++)
            af[i] = *(const short8*)&As[wr + i * 16 + l16][quad * 8];
        #pragma unroll
        for (int j = 0; j < 4; j++)
            bf[j] = *(const short8*)&Bs[wc + j * 16 + l16][quad * 8];
        #pragma unroll
        for (int i = 0; i < 4; i++)
            #pragma unroll
            for (int j = 0; j < 4; j++)
                acc[i][j] = __builtin_amdgcn_mfma_f32_16x16x32_bf16(
                    af[i], bf[j], acc[i][j], 0, 0, 0);
    }
    // C/D layout (verified m89/m91): col = lane&15, row = quad*4 + reg
    #pragma unroll
    for (int i = 0; i < 4; i++) {
        #pragma unroll
        for (int j = 0; j < 4; j++) {
            int rbase = row0 + wr + i * 16 + quad * 4;
            int cg = col0 + wc + j * 16 + l16;
            #pragma unroll
            for (int r = 0; r < 4; r++) {
                if (OUT_F32)
                    ((float*)Cv)[(size_t)(rbase + r) * N + cg] = acc[i][j][r];
                else
                    ((uint16_t*)Cv)[(size_t)(rbase + r) * N + cg] = f2b(acc[i][j][r]);
            }
        }
    }
}

// ---------------- attention: flash-style, vector ALU, fp32 math ------------
// qkv: [B*T, 3*C] bf16 bits (q cols 0..1023, k 1024..2047, v 2048..3071)
// One block = 64 query rows for one (b,h). 4 threads/row, 16 dims each.
// Sink: init m = sink_logit[h], l = 1 (the sink column, V=0).
__global__ __launch_bounds__(256)
void attn_kernel(const uint16_t* __restrict__ qkv,
                 const float* __restrict__ sink,
                 uint16_t* __restrict__ y) {
    __shared__ float Ks[32][64];
    __shared__ float Vs[32][64];
    int tid = threadIdx.x;
    int r = tid >> 2;          // query row within tile: 0..63
    int sub = tid & 3;         // dim group: 16 dims each
    int qt = blockIdx.x;       // 0..31
    int bh = blockIdx.y;       // 0..31
    int b = bh >> 4, h = bh & 15;
    int q = qt * 64 + r;
    const float scale = 0.125f;  // 1/sqrt(64)

    float qf[16];
    {
        const uint16_t* qp = qkv + (size_t)(b * T_ + q) * 3072 + h * 64 + sub * 16;
        #pragma unroll
        for (int i = 0; i < 16; i++) qf[i] = bf2f(qp[i]) * scale;
    }

    float m = sink[h];
    float l = 1.0f;
    float o[16];
    #pragma unroll
    for (int i = 0; i < 16; i++) o[i] = 0.f;

    int ktiles = 2 * qt + 2;   // keys 0 .. qt*64+63 in tiles of 32
    for (int kt = 0; kt < ktiles; kt++) {
        __syncthreads();
        {   // stage K,V tile (32 keys x 64 dims) to LDS as fp32
            int kk = tid >> 3;
            int off = (tid & 7) * 8;
            size_t base = (size_t)(b * T_ + kt * 32 + kk) * 3072 + h * 64 + off;
            uint4 kv4 = *(const uint4*)(qkv + base + 1024);
            uint4 vv4 = *(const uint4*)(qkv + base + 2048);
            const uint16_t* kb = (const uint16_t*)&kv4;
            const uint16_t* vb = (const uint16_t*)&vv4;
            #pragma unroll
            for (int j = 0; j < 8; j++) {
                Ks[kk][off + j] = bf2f(kb[j]);
                Vs[kk][off + j] = bf2f(vb[j]);
            }
        }
        __syncthreads();
        int kmax = min(32, q - kt * 32 + 1);  // per-row causal trip count
        for (int kk = 0; kk < kmax; kk++) {
            const float* kr = &Ks[kk][sub * 16];
            float part = 0.f;
            #pragma unroll
            for (int i = 0; i < 16; i++) part += qf[i] * kr[i];
            part += __shfl_xor(part, 1);
            part += __shfl_xor(part, 2);   // all 4 lanes of row: full dot
            float s = part;
            float mn = fmaxf(m, s);
            float alpha = __expf(m - mn);
            float p = __expf(s - mn);
            l = l * alpha + p;
            m = mn;
            const float* vr = &Vs[kk][sub * 16];
            #pragma unroll
            for (int i = 0; i < 16; i++) o[i] = o[i] * alpha + p * vr[i];
        }
    }

    float inv = 1.0f / l;
    uint16_t* yp = y + (size_t)(b * T_ + q) * 1024 + h * 64 + sub * 16;
    #pragma unroll
    for (int i = 0; i < 16; i++) yp[i] = f2b(o[i] * inv);
}

extern "C" void kernel_launch(void* const* d_in, const int* in_sizes, int n_in,
                              void* d_out, int out_size, void* d_ws, size_t ws_size,
                              hipStream_t stream) {
    const float* x      = (const float*)d_in[0];  // [B,T,C] fp32
    const float* w_qkv  = (const float*)d_in[1];  // [C, 3HD] fp32
    const float* w_proj = (const float*)d_in[2];  // [HD, C] fp32
    const float* sink   = (const float*)d_in[3];  // [H] fp32
    float* out          = (float*)d_out;          // [B,T,C] fp32

    char* ws = (char*)d_ws;
    uint16_t* wt_qkv  = (uint16_t*)ws;                       // [3072,1024] 6.29 MB
    uint16_t* wt_proj = (uint16_t*)(ws + 6291456);           // [1024,1024] 2.10 MB
    uint16_t* x_c     = (uint16_t*)(ws + 8388608);           // [4096,1024] 8.39 MB
    uint16_t* qkv     = (uint16_t*)(ws + 16777216);          // [4096,3072] 25.17 MB
    uint16_t* yb      = (uint16_t*)(ws + 41943040);          // [4096,1024] 8.39 MB

    // 1) canonicalize x to bf16; transpose weights into B^T ([N,K]) bf16
    canon_x<<<4194304 / 1024, 256, 0, stream>>>(x, x_c, 4194304);
    transpose_conv<<<dim3(3072 / 32, 1024 / 32), dim3(32, 8), 0, stream>>>(
        w_qkv, wt_qkv, 1024, 3072);
    transpose_conv<<<dim3(1024 / 32, 1024 / 32), dim3(32, 8), 0, stream>>>(
        w_proj, wt_proj, 1024, 1024);

    // 2) qkv = x @ w_qkv   [4096,1024]x[1024,3072] -> bf16
    gemm_bt<false><<<dim3(4096 / 128, 3072 / 128), 256, 0, stream>>>(
        x_c, wt_qkv, qkv, 4096, 3072, 1024);

    // 3) attention with sink -> yb bf16
    attn_kernel<<<dim3(T_ / 64, B_ * H_), 256, 0, stream>>>(qkv, sink, yb);

    // 4) out = y @ w_proj  [4096,1024]x[1024,1024] -> fp32
    gemm_bt<true><<<dim3(4096 / 128, 1024 / 128), 256, 0, stream>>>(
        yb, wt_proj, out, 4096, 1024, 1024);
}

// Round 4
// 238.963 us; speedup vs baseline: 4.5045x; 4.5045x over previous
//
#include <hip/hip_runtime.h>
#include <hip/hip_bf16.h>
#include <stdint.h>

#define B_ 2
#define T_ 2048
#define C_ 1024
#define H_ 16
#define D_ 64

typedef __attribute__((ext_vector_type(8))) short short8;
typedef __attribute__((ext_vector_type(4))) float floatx4;

__device__ __forceinline__ float bf2f(uint16_t b) {
    return __uint_as_float(((uint32_t)b) << 16);
}
__device__ __forceinline__ uint16_t f2b(float f) {
    __hip_bfloat16 h = __float2bfloat16(f);  // RNE
    return *(uint16_t*)&h;
}
__device__ __forceinline__ void glds16(const uint16_t* g, uint16_t* l) {
    __builtin_amdgcn_global_load_lds(
        (const __attribute__((address_space(1))) uint32_t*)g,
        (__attribute__((address_space(3))) uint32_t*)l, 16, 0, 0);
}

// ---- canonicalize x: fp32 -> bf16 -----------------------------------------
__global__ void canon_x(const float* __restrict__ in, uint16_t* __restrict__ out,
                        int n) {
    int i = (blockIdx.x * 256 + threadIdx.x) * 4;
    if (i >= n) return;
    float4 v = *(const float4*)(in + i);
    out[i + 0] = f2b(v.x);
    out[i + 1] = f2b(v.y);
    out[i + 2] = f2b(v.z);
    out[i + 3] = f2b(v.w);
}

// ---- transpose + convert: in [R,W] fp32 -> out [W,R] bf16 -----------------
__global__ void transpose_conv(const float* __restrict__ in, uint16_t* __restrict__ out,
                               int R, int W) {
    __shared__ uint16_t tile[32][33];
    int tx = threadIdx.x, ty = threadIdx.y;
    int c0 = blockIdx.x * 32, r0 = blockIdx.y * 32;
    #pragma unroll
    for (int i = 0; i < 32; i += 8)
        tile[ty + i][tx] = f2b(in[(size_t)(r0 + ty + i) * W + (c0 + tx)]);
    __syncthreads();
    #pragma unroll
    for (int i = 0; i < 32; i += 8)
        out[(size_t)(c0 + ty + i) * R + (r0 + tx)] = tile[tx][ty + i];
}

// ------- GEMM: C[M,N] = A[M,K] @ Bt[N,K]^T ; bf16 in, fp32 acc -------------
// 128x128 tile, 4 waves; m97 structure: global_load_lds width-16 staging.
template <bool OUT_F32>
__global__ __launch_bounds__(256)
void gemm_bt(const uint16_t* __restrict__ A, const uint16_t* __restrict__ Bt,
             void* __restrict__ Cv, int M, int N, int K) {
    __shared__ uint16_t As[128][32];   // 8 KB, no pad (glds lane-contiguous)
    __shared__ uint16_t Bs[128][32];
    int tid = threadIdx.x;
    int wave = tid >> 6, lane = tid & 63;
    int quad = lane >> 4, l16 = lane & 15;
    int wr = (wave >> 1) * 64, wc = (wave & 1) * 64;
    int row0 = blockIdx.x * 128, col0 = blockIdx.y * 128;

    // staging map: lds u16 off = wave*1024 + j*512 + lane*8  (== lane*16B) ✓
    int srow = wave * 32 + (lane >> 2);
    int scol = (lane & 3) * 8;
    const uint16_t* gA1 = A + (size_t)(row0 + srow) * K + scol;
    const uint16_t* gA2 = A + (size_t)(row0 + srow + 16) * K + scol;
    const uint16_t* gB1 = Bt + (size_t)(col0 + srow) * K + scol;
    const uint16_t* gB2 = Bt + (size_t)(col0 + srow + 16) * K + scol;
    uint16_t* lA1 = &As[srow][scol];
    uint16_t* lA2 = &As[srow + 16][scol];
    uint16_t* lB1 = &Bs[srow][scol];
    uint16_t* lB2 = &Bs[srow + 16][scol];

    floatx4 acc[4][4];
    #pragma unroll
    for (int i = 0; i < 4; i++)
        #pragma unroll
        for (int j = 0; j < 4; j++)
            acc[i][j] = (floatx4){0.f, 0.f, 0.f, 0.f};

    for (int k0 = 0; k0 < K; k0 += 32) {
        __syncthreads();
        glds16(gA1 + k0, lA1);
        glds16(gA2 + k0, lA2);
        glds16(gB1 + k0, lB1);
        glds16(gB2 + k0, lB2);
        __syncthreads();
        short8 af[4], bf[4];
        #pragma unroll
        for (int i = 0; i < 4; i++)
            af[i] = *(const short8*)&As[wr + i * 16 + l16][quad * 8];
        #pragma unroll
        for (int j = 0; j < 4; j++)
            bf[j] = *(const short8*)&Bs[wc + j * 16 + l16][quad * 8];
        #pragma unroll
        for (int i = 0; i < 4; i++)
            #pragma unroll
            for (int j = 0; j < 4; j++)
                acc[i][j] = __builtin_amdgcn_mfma_f32_16x16x32_bf16(
                    af[i], bf[j], acc[i][j], 0, 0, 0);
    }
    // C/D layout: col = lane&15, row = quad*4 + reg
    #pragma unroll
    for (int i = 0; i < 4; i++) {
        #pragma unroll
        for (int j = 0; j < 4; j++) {
            int rbase = row0 + wr + i * 16 + quad * 4;
            int cg = col0 + wc + j * 16 + l16;
            #pragma unroll
            for (int r = 0; r < 4; r++) {
                if (OUT_F32)
                    ((float*)Cv)[(size_t)(rbase + r) * N + cg] = acc[i][j][r];
                else
                    ((uint16_t*)Cv)[(size_t)(rbase + r) * N + cg] = f2b(acc[i][j][r]);
            }
        }
    }
}

// ---------------- MFMA flash attention with sink ---------------------------
// Block: 128 q rows of one (b,h); 4 waves x 32 q rows. Key tiles of 64.
// S^T = K*Q^T (so q = lane&15 in softmax layout); P via LDS; O += P*V.
__global__ __launch_bounds__(256)
void attn_mfma(const uint16_t* __restrict__ qkv,
               const float* __restrict__ sink,
               uint16_t* __restrict__ y) {
    __shared__ uint16_t Ks[64][72];     // [key][d]  9216 B (pad 8 -> 144B rows)
    __shared__ uint16_t Vt[64][72];     // [d][key]  9216 B
    __shared__ uint16_t Pl[4][32][72];  // per-wave [q][key] 18432 B

    int tid = threadIdx.x;
    int w = tid >> 6;
    int lane = tid & 63;
    int quad = lane >> 4, l16 = lane & 15;

    int qb = (gridDim.x - 1) - blockIdx.x;  // big blocks first
    int bh = blockIdx.y;
    int b = bh >> 4, h = bh & 15;
    int q0w = qb * 128 + w * 32;            // wave's first q row
    int qmaxw = q0w + 31;

    const uint16_t* qkv_b = qkv + (size_t)b * T_ * 3072;

    // ---- Q fragments (2 qtiles x 2 kd), pre-scaled by 1/8 (exact) ----
    short8 qf[2][2];
    #pragma unroll
    for (int qt = 0; qt < 2; qt++) {
        int qrow = q0w + qt * 16 + l16;
        #pragma unroll
        for (int kd = 0; kd < 2; kd++) {
            uint4 raw = *(const uint4*)(qkv_b + (size_t)qrow * 3072 + h * 64 +
                                        kd * 32 + quad * 8);
            const uint16_t* rp = (const uint16_t*)&raw;
            short8 f;
            #pragma unroll
            for (int j = 0; j < 8; j++)
                f[j] = (short)f2b(bf2f(rp[j]) * 0.125f);
            qf[qt][kd] = f;
        }
    }

    float m_s[2], l_s[2];
    m_s[0] = m_s[1] = sink[h];
    l_s[0] = l_s[1] = 1.0f;
    floatx4 acc_o[2][4];
    #pragma unroll
    for (int qt = 0; qt < 2; qt++)
        #pragma unroll
        for (int dt = 0; dt < 4; dt++)
            acc_o[qt][dt] = (floatx4){0.f, 0.f, 0.f, 0.f};

    int ktiles = 2 * qb + 2;
    for (int kt = 0; kt < ktiles; kt++) {
        __syncthreads();
        {   // ---- stage K[64][64] and V^T[64][64] (256 threads) ----
            int t2 = tid >> 3;     // key-row pair 0..31
            int dg = tid & 7;      // d-group of 8
            const uint16_t* kb_ = qkv_b + (size_t)(kt * 64) * 3072 + 1024 + h * 64;
            const uint16_t* vb_ = kb_ + 1024;
            uint4 k0v = *(const uint4*)(kb_ + (size_t)(2 * t2) * 3072 + dg * 8);
            uint4 k1v = *(const uint4*)(kb_ + (size_t)(2 * t2 + 1) * 3072 + dg * 8);
            *(uint4*)&Ks[2 * t2][dg * 8] = k0v;
            *(uint4*)&Ks[2 * t2 + 1][dg * 8] = k1v;
            uint4 v0v = *(const uint4*)(vb_ + (size_t)(2 * t2) * 3072 + dg * 8);
            uint4 v1v = *(const uint4*)(vb_ + (size_t)(2 * t2 + 1) * 3072 + dg * 8);
            const uint16_t* a0 = (const uint16_t*)&v0v;
            const uint16_t* a1 = (const uint16_t*)&v1v;
            #pragma unroll
            for (int j = 0; j < 8; j++)
                *(uint32_t*)&Vt[dg * 8 + j][2 * t2] =
                    (uint32_t)a0[j] | ((uint32_t)a1[j] << 16);
        }
        __syncthreads();

        if (kt * 64 > qmaxw) continue;  // fully masked for this wave

        // ---- S^T = K * Q^T : acc_s[qt][rt], key=rt*16+quad*4+r, q=qt*16+l16
        floatx4 acc_s[2][4];
        #pragma unroll
        for (int qt = 0; qt < 2; qt++)
            #pragma unroll
            for (int rt = 0; rt < 4; rt++)
                acc_s[qt][rt] = (floatx4){0.f, 0.f, 0.f, 0.f};
        #pragma unroll
        for (int rt = 0; rt < 4; rt++) {
            short8 kf0 = *(const short8*)&Ks[rt * 16 + l16][quad * 8];
            short8 kf1 = *(const short8*)&Ks[rt * 16 + l16][32 + quad * 8];
            #pragma unroll
            for (int qt = 0; qt < 2; qt++) {
                acc_s[qt][rt] = __builtin_amdgcn_mfma_f32_16x16x32_bf16(
                    kf0, qf[qt][0], acc_s[qt][rt], 0, 0, 0);
                acc_s[qt][rt] = __builtin_amdgcn_mfma_f32_16x16x32_bf16(
                    kf1, qf[qt][1], acc_s[qt][rt], 0, 0, 0);
            }
        }
        // ---- causal mask (diagonal tiles only) ----
        if (kt * 64 + 63 > q0w) {
            #pragma unroll
            for (int qt = 0; qt < 2; qt++) {
                int qg = q0w + qt * 16 + l16;
                #pragma unroll
                for (int rt = 0; rt < 4; rt++) {
                    int kg = kt * 64 + rt * 16 + quad * 4;
                    #pragma unroll
                    for (int r = 0; r < 4; r++)
                        if (kg + r > qg) acc_s[qt][rt][r] = -1e30f;
                }
            }
        }
        // ---- online softmax + P write + O rescale ----
        #pragma unroll
        for (int qt = 0; qt < 2; qt++) {
            float mx = -1e30f;
            #pragma unroll
            for (int rt = 0; rt < 4; rt++)
                #pragma unroll
                for (int r = 0; r < 4; r++) mx = fmaxf(mx, acc_s[qt][rt][r]);
            mx = fmaxf(mx, __shfl_xor(mx, 16));
            mx = fmaxf(mx, __shfl_xor(mx, 32));
            float mnew = fmaxf(m_s[qt], mx);
            float alpha = __expf(m_s[qt] - mnew);
            m_s[qt] = mnew;
            float psum = 0.f;
            #pragma unroll
            for (int rt = 0; rt < 4; rt++) {
                float p0 = __expf(acc_s[qt][rt][0] - mnew);
                float p1 = __expf(acc_s[qt][rt][1] - mnew);
                float p2 = __expf(acc_s[qt][rt][2] - mnew);
                float p3 = __expf(acc_s[qt][rt][3] - mnew);
                psum += (p0 + p1) + (p2 + p3);
                uint2 pk;
                pk.x = (uint32_t)f2b(p0) | ((uint32_t)f2b(p1) << 16);
                pk.y = (uint32_t)f2b(p2) | ((uint32_t)f2b(p3) << 16);
                *(uint2*)&Pl[w][qt * 16 + l16][rt * 16 + quad * 4] = pk;
            }
            psum += __shfl_xor(psum, 16);
            psum += __shfl_xor(psum, 32);
            l_s[qt] = l_s[qt] * alpha + psum;
            #pragma unroll
            for (int r = 0; r < 4; r++) {
                float ar = __shfl(alpha, (lane & 48) | (quad * 4 + r));
                #pragma unroll
                for (int dt = 0; dt < 4; dt++) acc_o[qt][dt][r] *= ar;
            }
        }
        // ---- O += P * V ----
        short8 vf[4][2];
        #pragma unroll
        for (int dt = 0; dt < 4; dt++)
            #pragma unroll
            for (int kb = 0; kb < 2; kb++)
                vf[dt][kb] = *(const short8*)&Vt[dt * 16 + l16][kb * 32 + quad * 8];
        #pragma unroll
        for (int qt = 0; qt < 2; qt++) {
            #pragma unroll
            for (int kb = 0; kb < 2; kb++) {
                short8 pf = *(const short8*)&Pl[w][qt * 16 + l16][kb * 32 + quad * 8];
                #pragma unroll
                for (int dt = 0; dt < 4; dt++)
                    acc_o[qt][dt] = __builtin_amdgcn_mfma_f32_16x16x32_bf16(
                        pf, vf[dt][kb], acc_o[qt][dt], 0, 0, 0);
            }
        }
    }

    // ---- epilogue: normalize by l (per-q via in-quad shuffle), store bf16 --
    #pragma unroll
    for (int qt = 0; qt < 2; qt++) {
        #pragma unroll
        for (int r = 0; r < 4; r++) {
            float lr = __shfl(l_s[qt], (lane & 48) | (quad * 4 + r));
            float inv = 1.0f / lr;
            int qg = q0w + qt * 16 + quad * 4 + r;
            uint16_t* yp = y + (size_t)(b * T_ + qg) * 1024 + h * 64;
            #pragma unroll
            for (int dt = 0; dt < 4; dt++)
                yp[dt * 16 + l16] = f2b(acc_o[qt][dt][r] * inv);
        }
    }
}

extern "C" void kernel_launch(void* const* d_in, const int* in_sizes, int n_in,
                              void* d_out, int out_size, void* d_ws, size_t ws_size,
                              hipStream_t stream) {
    const float* x      = (const float*)d_in[0];  // [B,T,C] fp32
    const float* w_qkv  = (const float*)d_in[1];  // [C, 3HD] fp32
    const float* w_proj = (const float*)d_in[2];  // [HD, C] fp32
    const float* sink   = (const float*)d_in[3];  // [H] fp32
    float* out          = (float*)d_out;          // [B,T,C] fp32

    char* ws = (char*)d_ws;
    uint16_t* wt_qkv  = (uint16_t*)ws;                       // [3072,1024] 6.29 MB
    uint16_t* wt_proj = (uint16_t*)(ws + 6291456);           // [1024,1024] 2.10 MB
    uint16_t* x_c     = (uint16_t*)(ws + 8388608);           // [4096,1024] 8.39 MB
    uint16_t* qkv     = (uint16_t*)(ws + 16777216);          // [4096,3072] 25.17 MB
    uint16_t* yb      = (uint16_t*)(ws + 41943040);          // [4096,1024] 8.39 MB

    canon_x<<<4194304 / 1024, 256, 0, stream>>>(x, x_c, 4194304);
    transpose_conv<<<dim3(3072 / 32, 1024 / 32), dim3(32, 8), 0, stream>>>(
        w_qkv, wt_qkv, 1024, 3072);
    transpose_conv<<<dim3(1024 / 32, 1024 / 32), dim3(32, 8), 0, stream>>>(
        w_proj, wt_proj, 1024, 1024);

    gemm_bt<false><<<dim3(4096 / 128, 3072 / 128), 256, 0, stream>>>(
        x_c, wt_qkv, qkv, 4096, 3072, 1024);

    attn_mfma<<<dim3(T_ / 128, B_ * H_), 256, 0, stream>>>(qkv, sink, yb);

    gemm_bt<true><<<dim3(4096 / 128, 1024 / 128), 256, 0, stream>>>(
        yb, wt_proj, out, 4096, 1024, 1024);
}

// Round 5
// 219.539 us; speedup vs baseline: 4.9031x; 1.0885x over previous
//
#include <hip/hip_runtime.h>
#include <hip/hip_bf16.h>
#include <stdint.h>

#define B_ 2
#define T_ 2048
#define C_ 1024
#define H_ 16
#define D_ 64

typedef __attribute__((ext_vector_type(8))) short short8;
typedef __attribute__((ext_vector_type(4))) float floatx4;

__device__ __forceinline__ float bf2f(uint16_t b) {
    return __uint_as_float(((uint32_t)b) << 16);
}
__device__ __forceinline__ uint16_t f2b(float f) {
    __hip_bfloat16 h = __float2bfloat16(f);  // RNE
    return *(uint16_t*)&h;
}
__device__ __forceinline__ void glds16(const uint16_t* g, uint16_t* l) {
    __builtin_amdgcn_global_load_lds(
        (const __attribute__((address_space(1))) uint32_t*)g,
        (__attribute__((address_space(3))) uint32_t*)l, 16, 0, 0);
}

// ---- canonicalize x: fp32 -> bf16 -----------------------------------------
__global__ void canon_x(const float* __restrict__ in, uint16_t* __restrict__ out,
                        int n) {
    int i = (blockIdx.x * 256 + threadIdx.x) * 4;
    if (i >= n) return;
    float4 v = *(const float4*)(in + i);
    out[i + 0] = f2b(v.x);
    out[i + 1] = f2b(v.y);
    out[i + 2] = f2b(v.z);
    out[i + 3] = f2b(v.w);
}

// ---- transpose + convert: in [R,W] fp32 -> out [W,R] bf16 -----------------
__global__ void transpose_conv(const float* __restrict__ in, uint16_t* __restrict__ out,
                               int R, int W) {
    __shared__ uint16_t tile[32][33];
    int tx = threadIdx.x, ty = threadIdx.y;
    int c0 = blockIdx.x * 32, r0 = blockIdx.y * 32;
    #pragma unroll
    for (int i = 0; i < 32; i += 8)
        tile[ty + i][tx] = f2b(in[(size_t)(r0 + ty + i) * W + (c0 + tx)]);
    __syncthreads();
    #pragma unroll
    for (int i = 0; i < 32; i += 8)
        out[(size_t)(c0 + ty + i) * R + (r0 + tx)] = tile[tx][ty + i];
}

// ------- GEMM: C[M,N] = A[M,K] @ Bt[N,K]^T ; bf16 in, fp32 acc -------------
template <bool OUT_F32>
__global__ __launch_bounds__(256)
void gemm_bt(const uint16_t* __restrict__ A, const uint16_t* __restrict__ Bt,
             void* __restrict__ Cv, int M, int N, int K) {
    __shared__ uint16_t As[128][32];
    __shared__ uint16_t Bs[128][32];
    int tid = threadIdx.x;
    int wave = tid >> 6, lane = tid & 63;
    int quad = lane >> 4, l16 = lane & 15;
    int wr = (wave >> 1) * 64, wc = (wave & 1) * 64;
    int row0 = blockIdx.x * 128, col0 = blockIdx.y * 128;

    int srow = wave * 32 + (lane >> 2);
    int scol = (lane & 3) * 8;
    const uint16_t* gA1 = A + (size_t)(row0 + srow) * K + scol;
    const uint16_t* gA2 = A + (size_t)(row0 + srow + 16) * K + scol;
    const uint16_t* gB1 = Bt + (size_t)(col0 + srow) * K + scol;
    const uint16_t* gB2 = Bt + (size_t)(col0 + srow + 16) * K + scol;
    uint16_t* lA1 = &As[srow][scol];
    uint16_t* lA2 = &As[srow + 16][scol];
    uint16_t* lB1 = &Bs[srow][scol];
    uint16_t* lB2 = &Bs[srow + 16][scol];

    floatx4 acc[4][4];
    #pragma unroll
    for (int i = 0; i < 4; i++)
        #pragma unroll
        for (int j = 0; j < 4; j++)
            acc[i][j] = (floatx4){0.f, 0.f, 0.f, 0.f};

    for (int k0 = 0; k0 < K; k0 += 32) {
        __syncthreads();
        glds16(gA1 + k0, lA1);
        glds16(gA2 + k0, lA2);
        glds16(gB1 + k0, lB1);
        glds16(gB2 + k0, lB2);
        __syncthreads();
        short8 af[4], bf[4];
        #pragma unroll
        for (int i = 0; i < 4; i++)
            af[i] = *(const short8*)&As[wr + i * 16 + l16][quad * 8];
        #pragma unroll
        for (int j = 0; j < 4; j++)
            bf[j] = *(const short8*)&Bs[wc + j * 16 + l16][quad * 8];
        #pragma unroll
        for (int i = 0; i < 4; i++)
            #pragma unroll
            for (int j = 0; j < 4; j++)
                acc[i][j] = __builtin_amdgcn_mfma_f32_16x16x32_bf16(
                    af[i], bf[j], acc[i][j], 0, 0, 0);
    }
    #pragma unroll
    for (int i = 0; i < 4; i++) {
        #pragma unroll
        for (int j = 0; j < 4; j++) {
            int rbase = row0 + wr + i * 16 + quad * 4;
            int cg = col0 + wc + j * 16 + l16;
            #pragma unroll
            for (int r = 0; r < 4; r++) {
                if (OUT_F32)
                    ((float*)Cv)[(size_t)(rbase + r) * N + cg] = acc[i][j][r];
                else
                    ((uint16_t*)Cv)[(size_t)(rbase + r) * N + cg] = f2b(acc[i][j][r]);
            }
        }
    }
}

// ---------------- MFMA flash attention with sink ---------------------------
// Block: 64 q rows of one (b,h); 4 waves x 16 q rows. Key tiles of 64.
// Register-prefetched K/V staging; XOR-swizzled V^T (kills 8-way conflicts);
// S^T = K*Q^T (q = lane&15 in softmax layout); P via per-wave LDS; O += P*V.
__global__ __launch_bounds__(256, 4)
void attn_mfma(const uint16_t* __restrict__ qkv,
               const float* __restrict__ sink,
               uint16_t* __restrict__ y) {
    __shared__ uint16_t Ks[64][72];     // [key][d]   9216 B
    __shared__ uint16_t Vt[64][72];     // [d][key]   9216 B (col-swizzled)
    __shared__ uint16_t Pl[4][16][72];  // per-wave [q][key] 9216 B

    int tid = threadIdx.x;
    int w = tid >> 6;
    int lane = tid & 63;
    int quad = lane >> 4, l16 = lane & 15;

    int qb = (gridDim.x - 1) - blockIdx.x;  // big blocks first
    int bh = blockIdx.y;
    int b = bh >> 4, h = bh & 15;
    int q0w = qb * 64 + w * 16;             // wave's first q row

    const uint16_t* qkv_b = qkv + (size_t)b * T_ * 3072;

    // ---- Q fragments (2 kd halves), pre-scaled by 1/8 (exact) ----
    short8 qf[2];
    #pragma unroll
    for (int kd = 0; kd < 2; kd++) {
        uint4 raw = *(const uint4*)(qkv_b + (size_t)(q0w + l16) * 3072 + h * 64 +
                                    kd * 32 + quad * 8);
        const uint16_t* rp = (const uint16_t*)&raw;
        short8 f;
        #pragma unroll
        for (int j = 0; j < 8; j++)
            f[j] = (short)f2b(bf2f(rp[j]) * 0.125f);
        qf[kd] = f;
    }

    float m_s = sink[h];
    float l_s = 1.0f;
    floatx4 acc_o[4];
    #pragma unroll
    for (int dt = 0; dt < 4; dt++) acc_o[dt] = (floatx4){0.f, 0.f, 0.f, 0.f};

    // ---- staging map: thread (t2,dg) handles key rows 2t2,2t2+1, dims dg*8..+7
    int t2 = tid >> 3;
    int dg = tid & 7;
    const uint16_t* kgp = qkv_b + 1024 + h * 64 + (size_t)(2 * t2) * 3072 + dg * 8;
    const uint16_t* vgp = kgp + 1024;
    int vcw = 2 * (t2 ^ (4 * dg));   // swizzled u16 col for V^T key-pair store

    int ktiles = qb + 1;
    // preload tile 0
    uint4 kr0 = *(const uint4*)(kgp);
    uint4 kr1 = *(const uint4*)(kgp + 3072);
    uint4 vr0 = *(const uint4*)(vgp);
    uint4 vr1 = *(const uint4*)(vgp + 3072);

    for (int kt = 0; kt < ktiles; kt++) {
        __syncthreads();
        // ---- store staged regs -> LDS ----
        *(uint4*)&Ks[2 * t2][dg * 8] = kr0;
        *(uint4*)&Ks[2 * t2 + 1][dg * 8] = kr1;
        {
            const uint16_t* a0 = (const uint16_t*)&vr0;
            const uint16_t* a1 = (const uint16_t*)&vr1;
            #pragma unroll
            for (int j = 0; j < 8; j++)
                *(uint32_t*)&Vt[dg * 8 + j][vcw] =
                    (uint32_t)a0[j] | ((uint32_t)a1[j] << 16);
        }
        __syncthreads();
        // ---- prefetch next tile into regs (overlaps with compute) ----
        if (kt + 1 < ktiles) {
            size_t off = (size_t)(kt + 1) * 64 * 3072;
            kr0 = *(const uint4*)(kgp + off);
            kr1 = *(const uint4*)(kgp + off + 3072);
            vr0 = *(const uint4*)(vgp + off);
            vr1 = *(const uint4*)(vgp + off + 3072);
        }
        if (kt * 64 > q0w + 15) continue;  // fully masked for this wave

        // ---- S^T = K * Q^T : key = rt*16+quad*4+r, q = l16 ----
        floatx4 acc_s[4];
        #pragma unroll
        for (int rt = 0; rt < 4; rt++) acc_s[rt] = (floatx4){0.f, 0.f, 0.f, 0.f};
        #pragma unroll
        for (int rt = 0; rt < 4; rt++) {
            short8 kf0 = *(const short8*)&Ks[rt * 16 + l16][quad * 8];
            short8 kf1 = *(const short8*)&Ks[rt * 16 + l16][32 + quad * 8];
            acc_s[rt] = __builtin_amdgcn_mfma_f32_16x16x32_bf16(
                kf0, qf[0], acc_s[rt], 0, 0, 0);
            acc_s[rt] = __builtin_amdgcn_mfma_f32_16x16x32_bf16(
                kf1, qf[1], acc_s[rt], 0, 0, 0);
        }
        // ---- causal mask (diagonal region only) ----
        int qg = q0w + l16;
        if (kt * 64 + 63 > q0w) {
            #pragma unroll
            for (int rt = 0; rt < 4; rt++) {
                int kg = kt * 64 + rt * 16 + quad * 4;
                #pragma unroll
                for (int r = 0; r < 4; r++)
                    if (kg + r > qg) acc_s[rt][r] = -1e30f;
            }
        }
        // ---- online softmax (q = l16; reduce across quads) ----
        float mx = -1e30f;
        #pragma unroll
        for (int rt = 0; rt < 4; rt++)
            #pragma unroll
            for (int r = 0; r < 4; r++) mx = fmaxf(mx, acc_s[rt][r]);
        mx = fmaxf(mx, __shfl_xor(mx, 16));
        mx = fmaxf(mx, __shfl_xor(mx, 32));
        float mnew = fmaxf(m_s, mx);
        float alpha = __expf(m_s - mnew);
        m_s = mnew;
        float psum = 0.f;
        #pragma unroll
        for (int rt = 0; rt < 4; rt++) {
            float p0 = __expf(acc_s[rt][0] - mnew);
            float p1 = __expf(acc_s[rt][1] - mnew);
            float p2 = __expf(acc_s[rt][2] - mnew);
            float p3 = __expf(acc_s[rt][3] - mnew);
            psum += (p0 + p1) + (p2 + p3);
            uint2 pk;
            pk.x = (uint32_t)f2b(p0) | ((uint32_t)f2b(p1) << 16);
            pk.y = (uint32_t)f2b(p2) | ((uint32_t)f2b(p3) << 16);
            *(uint2*)&Pl[w][l16][rt * 16 + quad * 4] = pk;
        }
        psum += __shfl_xor(psum, 16);
        psum += __shfl_xor(psum, 32);
        l_s = l_s * alpha + psum;
        #pragma unroll
        for (int r = 0; r < 4; r++) {
            float ar = __shfl(alpha, (lane & 48) | (quad * 4 + r));
            #pragma unroll
            for (int dt = 0; dt < 4; dt++) acc_o[dt][r] *= ar;
        }
        // ---- O += P * V (P from per-wave LDS; V^T reads de-swizzled) ----
        #pragma unroll
        for (int kb = 0; kb < 2; kb++) {
            short8 pf = *(const short8*)&Pl[w][l16][kb * 32 + quad * 8];
            #pragma unroll
            for (int dt = 0; dt < 4; dt++) {
                int d = dt * 16 + l16;
                int col = 2 * (((kb * 16) + quad * 4) ^ (4 * (d >> 3)));
                short8 vf = *(const short8*)&Vt[d][col];
                acc_o[dt] = __builtin_amdgcn_mfma_f32_16x16x32_bf16(
                    pf, vf, acc_o[dt], 0, 0, 0);
            }
        }
    }

    // ---- epilogue: normalize by l (per-q via in-quad shuffle), store bf16 --
    #pragma unroll
    for (int r = 0; r < 4; r++) {
        float lr = __shfl(l_s, (lane & 48) | (quad * 4 + r));
        float inv = 1.0f / lr;
        int qg = q0w + quad * 4 + r;
        uint16_t* yp = y + (size_t)(b * T_ + qg) * 1024 + h * 64;
        #pragma unroll
        for (int dt = 0; dt < 4; dt++)
            yp[dt * 16 + l16] = f2b(acc_o[dt][r] * inv);
    }
}

extern "C" void kernel_launch(void* const* d_in, const int* in_sizes, int n_in,
                              void* d_out, int out_size, void* d_ws, size_t ws_size,
                              hipStream_t stream) {
    const float* x      = (const float*)d_in[0];  // [B,T,C] fp32
    const float* w_qkv  = (const float*)d_in[1];  // [C, 3HD] fp32
    const float* w_proj = (const float*)d_in[2];  // [HD, C] fp32
    const float* sink   = (const float*)d_in[3];  // [H] fp32
    float* out          = (float*)d_out;          // [B,T,C] fp32

    char* ws = (char*)d_ws;
    uint16_t* wt_qkv  = (uint16_t*)ws;                       // [3072,1024] 6.29 MB
    uint16_t* wt_proj = (uint16_t*)(ws + 6291456);           // [1024,1024] 2.10 MB
    uint16_t* x_c     = (uint16_t*)(ws + 8388608);           // [4096,1024] 8.39 MB
    uint16_t* qkv     = (uint16_t*)(ws + 16777216);          // [4096,3072] 25.17 MB
    uint16_t* yb      = (uint16_t*)(ws + 41943040);          // [4096,1024] 8.39 MB

    canon_x<<<4194304 / 1024, 256, 0, stream>>>(x, x_c, 4194304);
    transpose_conv<<<dim3(3072 / 32, 1024 / 32), dim3(32, 8), 0, stream>>>(
        w_qkv, wt_qkv, 1024, 3072);
    transpose_conv<<<dim3(1024 / 32, 1024 / 32), dim3(32, 8), 0, stream>>>(
        w_proj, wt_proj, 1024, 1024);

    gemm_bt<false><<<dim3(4096 / 128, 3072 / 128), 256, 0, stream>>>(
        x_c, wt_qkv, qkv, 4096, 3072, 1024);

    attn_mfma<<<dim3(T_ / 64, B_ * H_), 256, 0, stream>>>(qkv, sink, yb);

    gemm_bt<true><<<dim3(4096 / 128, 1024 / 128), 256, 0, stream>>>(
        yb, wt_proj, out, 4096, 1024, 1024);
}

// Round 6
// 201.359 us; speedup vs baseline: 5.3458x; 1.0903x over previous
//
#include <hip/hip_runtime.h>
#include <hip/hip_bf16.h>
#include <stdint.h>

#define B_ 2
#define T_ 2048
#define C_ 1024
#define H_ 16
#define D_ 64

typedef __attribute__((ext_vector_type(8))) short short8;
typedef __attribute__((ext_vector_type(4))) float floatx4;

__device__ __forceinline__ float bf2f(uint16_t b) {
    return __uint_as_float(((uint32_t)b) << 16);
}
__device__ __forceinline__ uint16_t f2b(float f) {
    __hip_bfloat16 h = __float2bfloat16(f);  // RNE
    return *(uint16_t*)&h;
}
__device__ __forceinline__ void glds16(const uint16_t* g, uint16_t* l) {
    __builtin_amdgcn_global_load_lds(
        (const __attribute__((address_space(1))) uint32_t*)g,
        (__attribute__((address_space(3))) uint32_t*)l, 16, 0, 0);
}

// ---- canonicalize x: fp32 -> bf16 -----------------------------------------
__global__ void canon_x(const float* __restrict__ in, uint16_t* __restrict__ out,
                        int n) {
    int i = (blockIdx.x * 256 + threadIdx.x) * 4;
    if (i >= n) return;
    float4 v = *(const float4*)(in + i);
    out[i + 0] = f2b(v.x);
    out[i + 1] = f2b(v.y);
    out[i + 2] = f2b(v.z);
    out[i + 3] = f2b(v.w);
}

// ---- transpose + convert: in [R,W] fp32 -> out [W,R] bf16 -----------------
__global__ void transpose_conv(const float* __restrict__ in, uint16_t* __restrict__ out,
                               int R, int W) {
    __shared__ uint16_t tile[32][33];
    int tx = threadIdx.x, ty = threadIdx.y;
    int c0 = blockIdx.x * 32, r0 = blockIdx.y * 32;
    #pragma unroll
    for (int i = 0; i < 32; i += 8)
        tile[ty + i][tx] = f2b(in[(size_t)(r0 + ty + i) * W + (c0 + tx)]);
    __syncthreads();
    #pragma unroll
    for (int i = 0; i < 32; i += 8)
        out[(size_t)(c0 + ty + i) * R + (r0 + tx)] = tile[tx][ty + i];
}

// ------- GEMM: C[M,N] = A[M,K] @ Bt[N,K]^T ; bf16 in, fp32 acc -------------
template <bool OUT_F32>
__global__ __launch_bounds__(256)
void gemm_bt(const uint16_t* __restrict__ A, const uint16_t* __restrict__ Bt,
             void* __restrict__ Cv, int M, int N, int K) {
    __shared__ uint16_t As[128][32];
    __shared__ uint16_t Bs[128][32];
    int tid = threadIdx.x;
    int wave = tid >> 6, lane = tid & 63;
    int quad = lane >> 4, l16 = lane & 15;
    int wr = (wave >> 1) * 64, wc = (wave & 1) * 64;
    int row0 = blockIdx.x * 128, col0 = blockIdx.y * 128;

    int srow = wave * 32 + (lane >> 2);
    int scol = (lane & 3) * 8;
    const uint16_t* gA1 = A + (size_t)(row0 + srow) * K + scol;
    const uint16_t* gA2 = A + (size_t)(row0 + srow + 16) * K + scol;
    const uint16_t* gB1 = Bt + (size_t)(col0 + srow) * K + scol;
    const uint16_t* gB2 = Bt + (size_t)(col0 + srow + 16) * K + scol;
    uint16_t* lA1 = &As[srow][scol];
    uint16_t* lA2 = &As[srow + 16][scol];
    uint16_t* lB1 = &Bs[srow][scol];
    uint16_t* lB2 = &Bs[srow + 16][scol];

    floatx4 acc[4][4];
    #pragma unroll
    for (int i = 0; i < 4; i++)
        #pragma unroll
        for (int j = 0; j < 4; j++)
            acc[i][j] = (floatx4){0.f, 0.f, 0.f, 0.f};

    for (int k0 = 0; k0 < K; k0 += 32) {
        __syncthreads();
        glds16(gA1 + k0, lA1);
        glds16(gA2 + k0, lA2);
        glds16(gB1 + k0, lB1);
        glds16(gB2 + k0, lB2);
        __syncthreads();
        short8 af[4], bf[4];
        #pragma unroll
        for (int i = 0; i < 4; i++)
            af[i] = *(const short8*)&As[wr + i * 16 + l16][quad * 8];
        #pragma unroll
        for (int j = 0; j < 4; j++)
            bf[j] = *(const short8*)&Bs[wc + j * 16 + l16][quad * 8];
        #pragma unroll
        for (int i = 0; i < 4; i++)
            #pragma unroll
            for (int j = 0; j < 4; j++)
                acc[i][j] = __builtin_amdgcn_mfma_f32_16x16x32_bf16(
                    af[i], bf[j], acc[i][j], 0, 0, 0);
    }
    #pragma unroll
    for (int i = 0; i < 4; i++) {
        #pragma unroll
        for (int j = 0; j < 4; j++) {
            int rbase = row0 + wr + i * 16 + quad * 4;
            int cg = col0 + wc + j * 16 + l16;
            #pragma unroll
            for (int r = 0; r < 4; r++) {
                if (OUT_F32)
                    ((float*)Cv)[(size_t)(rbase + r) * N + cg] = acc[i][j][r];
                else
                    ((uint16_t*)Cv)[(size_t)(rbase + r) * N + cg] = f2b(acc[i][j][r]);
            }
        }
    }
}

// ---------------- MFMA flash attention with sink ---------------------------
// Pair-balanced: block (pair,bh) covers strips 31-pair (waves 0,1) and pair
// (waves 2,3); every block stages 32-pair ktiles, total work constant (33).
// 1D grid id = pair*32+bh so id%8 = bh%8 -> same-bh blocks share one XCD L2.
// Wave = 32 q rows (2 qt). Double-buffered K/V LDS, 1 barrier/ktile,
// register prefetch. S^T = K*Q^T; P via per-wave LDS; O += P*V.
__global__ __launch_bounds__(256, 2)
void attn_mfma(const uint16_t* __restrict__ qkv,
               const float* __restrict__ sink,
               uint16_t* __restrict__ y) {
    __shared__ uint16_t Ks[2][64][72];   // [buf][key][d]   18432 B
    __shared__ uint16_t Vt[2][64][72];   // [buf][d][key]   18432 B (swizzled)
    __shared__ uint16_t Pl[4][32][72];   // per-wave [q][key] 18432 B

    int tid = threadIdx.x;
    int w = tid >> 6, lane = tid & 63;
    int quad = lane >> 4, l16 = lane & 15;

    int id = blockIdx.x;
    int pair = id >> 5, bh = id & 31;
    int b = bh >> 4, h = bh & 15;
    int strip = (w < 2) ? (31 - pair) : pair;   // this wave's 64-q strip
    int q0w = strip * 64 + (w & 1) * 32;        // wave's first q row
    int ktiles = 32 - pair;                     // tiles staged by the block
    int myktiles = strip + 1;                   // tiles this wave computes

    const uint16_t* qkv_b = qkv + (size_t)b * T_ * 3072;

    // ---- Q fragments: 2 qt x 2 kd, pre-scaled by 1/8 (exact) ----
    short8 qf[2][2];
    #pragma unroll
    for (int qt = 0; qt < 2; qt++) {
        int qrow = q0w + qt * 16 + l16;
        #pragma unroll
        for (int kd = 0; kd < 2; kd++) {
            uint4 raw = *(const uint4*)(qkv_b + (size_t)qrow * 3072 + h * 64 +
                                        kd * 32 + quad * 8);
            const uint16_t* rp = (const uint16_t*)&raw;
            short8 f;
            #pragma unroll
            for (int j = 0; j < 8; j++)
                f[j] = (short)f2b(bf2f(rp[j]) * 0.125f);
            qf[qt][kd] = f;
        }
    }

    float m_s[2], l_s[2];
    m_s[0] = m_s[1] = sink[h];
    l_s[0] = l_s[1] = 1.0f;
    floatx4 acc_o[2][4];
    #pragma unroll
    for (int qt = 0; qt < 2; qt++)
        #pragma unroll
        for (int dt = 0; dt < 4; dt++)
            acc_o[qt][dt] = (floatx4){0.f, 0.f, 0.f, 0.f};

    // ---- staging map: thread (t2,dg): key rows 2t2,2t2+1, dims dg*8..+7 ----
    int t2 = tid >> 3;
    int dg = tid & 7;
    const uint16_t* kgp = qkv_b + 1024 + h * 64 + (size_t)(2 * t2) * 3072 + dg * 8;
    const uint16_t* vgp = kgp + 1024;
    int vcw = 2 * (t2 ^ (4 * dg));   // swizzled u16 col for V^T key-pair store

    uint4 kr0 = *(const uint4*)(kgp);
    uint4 kr1 = *(const uint4*)(kgp + 3072);
    uint4 vr0 = *(const uint4*)(vgp);
    uint4 vr1 = *(const uint4*)(vgp + 3072);
    // store tile 0 -> buf 0
    {
        *(uint4*)&Ks[0][2 * t2][dg * 8] = kr0;
        *(uint4*)&Ks[0][2 * t2 + 1][dg * 8] = kr1;
        const uint16_t* a0 = (const uint16_t*)&vr0;
        const uint16_t* a1 = (const uint16_t*)&vr1;
        #pragma unroll
        for (int j = 0; j < 8; j++)
            *(uint32_t*)&Vt[0][dg * 8 + j][vcw] =
                (uint32_t)a0[j] | ((uint32_t)a1[j] << 16);
    }
    if (ktiles > 1) {   // preload tile 1
        kr0 = *(const uint4*)(kgp + 64 * 3072);
        kr1 = *(const uint4*)(kgp + 64 * 3072 + 3072);
        vr0 = *(const uint4*)(vgp + 64 * 3072);
        vr1 = *(const uint4*)(vgp + 64 * 3072 + 3072);
    }
    __syncthreads();

    for (int kt = 0; kt < ktiles; kt++) {
        int cur = kt & 1;
        // ---- store prefetched tile kt+1 into the other buffer ----
        if (kt + 1 < ktiles) {
            *(uint4*)&Ks[cur ^ 1][2 * t2][dg * 8] = kr0;
            *(uint4*)&Ks[cur ^ 1][2 * t2 + 1][dg * 8] = kr1;
            const uint16_t* a0 = (const uint16_t*)&vr0;
            const uint16_t* a1 = (const uint16_t*)&vr1;
            #pragma unroll
            for (int j = 0; j < 8; j++)
                *(uint32_t*)&Vt[cur ^ 1][dg * 8 + j][vcw] =
                    (uint32_t)a0[j] | ((uint32_t)a1[j] << 16);
        }
        // ---- issue prefetch of tile kt+2 (lands during this iter) ----
        if (kt + 2 < ktiles) {
            size_t off = (size_t)(kt + 2) * 64 * 3072;
            kr0 = *(const uint4*)(kgp + off);
            kr1 = *(const uint4*)(kgp + off + 3072);
            vr0 = *(const uint4*)(vgp + off);
            vr1 = *(const uint4*)(vgp + off + 3072);
        }
        if (kt < myktiles) {
            // ---- K and V fragments (shared by both qt) ----
            short8 kf[4][2];
            #pragma unroll
            for (int rt = 0; rt < 4; rt++) {
                kf[rt][0] = *(const short8*)&Ks[cur][rt * 16 + l16][quad * 8];
                kf[rt][1] = *(const short8*)&Ks[cur][rt * 16 + l16][32 + quad * 8];
            }
            short8 vf[2][4];
            #pragma unroll
            for (int kb = 0; kb < 2; kb++)
                #pragma unroll
                for (int dt = 0; dt < 4; dt++) {
                    int d = dt * 16 + l16;
                    int col = 2 * (((kb * 16) + quad * 4) ^ (4 * (d >> 3)));
                    vf[kb][dt] = *(const short8*)&Vt[cur][d][col];
                }
            #pragma unroll
            for (int qt = 0; qt < 2; qt++) {
                // ---- S^T = K * Q^T : key = rt*16+quad*4+r, q = l16 ----
                floatx4 acc_s[4];
                #pragma unroll
                for (int rt = 0; rt < 4; rt++)
                    acc_s[rt] = (floatx4){0.f, 0.f, 0.f, 0.f};
                #pragma unroll
                for (int rt = 0; rt < 4; rt++) {
                    acc_s[rt] = __builtin_amdgcn_mfma_f32_16x16x32_bf16(
                        kf[rt][0], qf[qt][0], acc_s[rt], 0, 0, 0);
                    acc_s[rt] = __builtin_amdgcn_mfma_f32_16x16x32_bf16(
                        kf[rt][1], qf[qt][1], acc_s[rt], 0, 0, 0);
                }
                // ---- causal mask: only the strip-diagonal tile ----
                if (kt == strip) {
                    int qg = q0w + qt * 16 + l16;
                    #pragma unroll
                    for (int rt = 0; rt < 4; rt++) {
                        int kg = kt * 64 + rt * 16 + quad * 4;
                        #pragma unroll
                        for (int r = 0; r < 4; r++)
                            if (kg + r > qg) acc_s[rt][r] = -1e30f;
                    }
                }
                // ---- online softmax (q = l16; reduce across quads) ----
                float mx = -1e30f;
                #pragma unroll
                for (int rt = 0; rt < 4; rt++)
                    #pragma unroll
                    for (int r = 0; r < 4; r++) mx = fmaxf(mx, acc_s[rt][r]);
                mx = fmaxf(mx, __shfl_xor(mx, 16));
                mx = fmaxf(mx, __shfl_xor(mx, 32));
                float mnew = fmaxf(m_s[qt], mx);
                float alpha = __expf(m_s[qt] - mnew);
                m_s[qt] = mnew;
                float psum = 0.f;
                #pragma unroll
                for (int rt = 0; rt < 4; rt++) {
                    float p0 = __expf(acc_s[rt][0] - mnew);
                    float p1 = __expf(acc_s[rt][1] - mnew);
                    float p2 = __expf(acc_s[rt][2] - mnew);
                    float p3 = __expf(acc_s[rt][3] - mnew);
                    psum += (p0 + p1) + (p2 + p3);
                    uint2 pk;
                    pk.x = (uint32_t)f2b(p0) | ((uint32_t)f2b(p1) << 16);
                    pk.y = (uint32_t)f2b(p2) | ((uint32_t)f2b(p3) << 16);
                    *(uint2*)&Pl[w][qt * 16 + l16][rt * 16 + quad * 4] = pk;
                }
                psum += __shfl_xor(psum, 16);
                psum += __shfl_xor(psum, 32);
                l_s[qt] = l_s[qt] * alpha + psum;
                #pragma unroll
                for (int r = 0; r < 4; r++) {
                    float ar = __shfl(alpha, (lane & 48) | (quad * 4 + r));
                    #pragma unroll
                    for (int dt = 0; dt < 4; dt++) acc_o[qt][dt][r] *= ar;
                }
                // ---- O += P * V ----
                #pragma unroll
                for (int kb = 0; kb < 2; kb++) {
                    short8 pf = *(const short8*)&Pl[w][qt * 16 + l16][kb * 32 + quad * 8];
                    #pragma unroll
                    for (int dt = 0; dt < 4; dt++)
                        acc_o[qt][dt] = __builtin_amdgcn_mfma_f32_16x16x32_bf16(
                            pf, vf[kb][dt], acc_o[qt][dt], 0, 0, 0);
                }
            }
        }
        __syncthreads();
    }

    // ---- epilogue: normalize by l (per-q via in-quad shuffle), store bf16 --
    #pragma unroll
    for (int qt = 0; qt < 2; qt++) {
        #pragma unroll
        for (int r = 0; r < 4; r++) {
            float lr = __shfl(l_s[qt], (lane & 48) | (quad * 4 + r));
            float inv = 1.0f / lr;
            int qg = q0w + qt * 16 + quad * 4 + r;
            uint16_t* yp = y + (size_t)(b * T_ + qg) * 1024 + h * 64;
            #pragma unroll
            for (int dt = 0; dt < 4; dt++)
                yp[dt * 16 + l16] = f2b(acc_o[qt][dt][r] * inv);
        }
    }
}

extern "C" void kernel_launch(void* const* d_in, const int* in_sizes, int n_in,
                              void* d_out, int out_size, void* d_ws, size_t ws_size,
                              hipStream_t stream) {
    const float* x      = (const float*)d_in[0];  // [B,T,C] fp32
    const float* w_qkv  = (const float*)d_in[1];  // [C, 3HD] fp32
    const float* w_proj = (const float*)d_in[2];  // [HD, C] fp32
    const float* sink   = (const float*)d_in[3];  // [H] fp32
    float* out          = (float*)d_out;          // [B,T,C] fp32

    char* ws = (char*)d_ws;
    uint16_t* wt_qkv  = (uint16_t*)ws;                       // [3072,1024] 6.29 MB
    uint16_t* wt_proj = (uint16_t*)(ws + 6291456);           // [1024,1024] 2.10 MB
    uint16_t* x_c     = (uint16_t*)(ws + 8388608);           // [4096,1024] 8.39 MB
    uint16_t* qkv     = (uint16_t*)(ws + 16777216);          // [4096,3072] 25.17 MB
    uint16_t* yb      = (uint16_t*)(ws + 41943040);          // [4096,1024] 8.39 MB

    canon_x<<<4194304 / 1024, 256, 0, stream>>>(x, x_c, 4194304);
    transpose_conv<<<dim3(3072 / 32, 1024 / 32), dim3(32, 8), 0, stream>>>(
        w_qkv, wt_qkv, 1024, 3072);
    transpose_conv<<<dim3(1024 / 32, 1024 / 32), dim3(32, 8), 0, stream>>>(
        w_proj, wt_proj, 1024, 1024);

    gemm_bt<false><<<dim3(4096 / 128, 3072 / 128), 256, 0, stream>>>(
        x_c, wt_qkv, qkv, 4096, 3072, 1024);

    // pair-balanced grid: id = pair*32 + bh  (id%8 == bh%8 -> XCD locality)
    attn_mfma<<<dim3(16 * 32), 256, 0, stream>>>(qkv, sink, yb);

    gemm_bt<true><<<dim3(4096 / 128, 1024 / 128), 256, 0, stream>>>(
        yb, wt_proj, out, 4096, 1024, 1024);
}